// Round 1
// baseline (329.752 us; speedup 1.0000x reference)
//
#include <hip/hip_runtime.h>
#include <hip/hip_bf16.h>

#define NTOK 49
#define NPAD 64
#define CDIM 128
#define C3   384
#define NHEAD 4
#define HDIM 32
#define SCALE 0.17677669529663687f

typedef __attribute__((ext_vector_type(8))) __bf16 bf16x8;
typedef __attribute__((ext_vector_type(4))) __bf16 bf16x4;
typedef __attribute__((ext_vector_type(4))) float f32x4;

// ws layout (bytes):
//   qkvT  __bf16[384][128]  @ 0        (98304 B)   qkvT[n][k] = qkv_w[k][n]
//   projT __bf16[128][128]  @ 98304    (32768 B)   projT[n][k] = proj_w[k][n]
//   blut  float [4][64][64] @ 131072   (65536 B)   rel-bias LUT, col>=49 -> -1e30
// total 196608 B

__global__ __launch_bounds__(256) void prep_kernel(
    const float* __restrict__ qkv_w, const float* __restrict__ proj_w,
    const float* __restrict__ bias_table,
    __bf16* __restrict__ qkvT, __bf16* __restrict__ projT, float* __restrict__ blut)
{
  int t = blockIdx.x * 256 + threadIdx.x;
  if (t < CDIM * C3) {                       // 49152
    int k = t / C3, n = t % C3;
    qkvT[n * CDIM + k] = (__bf16)qkv_w[t];
  } else if (t < CDIM * C3 + CDIM * CDIM) {  // +16384
    int t2 = t - CDIM * C3;
    int k = t2 / CDIM, n = t2 % CDIM;
    projT[n * CDIM + k] = (__bf16)proj_w[t2];
  } else if (t < CDIM * C3 + CDIM * CDIM + NHEAD * NPAD * NPAD) {  // +16384
    int t3 = t - (CDIM * C3 + CDIM * CDIM);
    int h = t3 >> 12, r = (t3 >> 6) & 63, c = t3 & 63;
    float v;
    if (c >= NTOK) v = -1e30f;           // softmax mask for padded key columns
    else if (r >= NTOK) v = 0.0f;        // padded query rows: finite, never stored
    else {
      int idx = (r / 7 - c / 7 + 6) * 13 + (r % 7 - c % 7 + 6);
      v = bias_table[idx * NHEAD + h];
    }
    blut[t3] = v;
  }
}

__global__ __launch_bounds__(256, 2) void attn_kernel(
    const float* __restrict__ x, const float* __restrict__ qkv_b,
    const float* __restrict__ proj_b,
    const __bf16* __restrict__ qkvT, const __bf16* __restrict__ projT,
    const float* __restrict__ blut, float* __restrict__ out)
{
  // LDS: qs[64][136] (later aliased as O) | ks[64][136] | vT[128][72] | P[64][72]
  // strides 136/72 bf16 = 272/144 B: 16B-aligned rows, bank offset 4 mod 32 -> 2-way (free)
  __shared__ __align__(16) char smem[62464];
  __bf16* qs_ = (__bf16*)smem;              // 8704 elems
  __bf16* ks_ = qs_ + NPAD * 136;           // 8704
  __bf16* vT_ = ks_ + NPAD * 136;           // 128*72 = 9216
  __bf16* Pm_ = vT_ + CDIM * 72;            // 64*72  = 4608

  const int tid  = threadIdx.x;
  const int wave = tid >> 6;
  const int lane = tid & 63;
  const int l15  = lane & 15;
  const int lg   = lane >> 4;
  const int m0   = wave * 16;               // wave's M-tile rows

  const int win = blockIdx.x;
  const int b  = win >> 6;
  const int wh = (win >> 3) & 7;
  const int ww = win & 7;
  const float* xbase = x + (((b * 56) + wh * 7) * 56 + ww * 7) * CDIM;

  // ---- weight B-fragments for qkv GEMM, wave-chunked over N (read once/block) ----
  const int nb = wave * 96;
  bf16x8 bq[6][4];
  #pragma unroll
  for (int nt = 0; nt < 6; ++nt)
    #pragma unroll
    for (int kt = 0; kt < 4; ++kt)
      bq[nt][kt] = *(const bf16x8*)(qkvT + (nb + nt * 16 + l15) * CDIM + kt * 32 + lg * 8);

  float qb[6];
  #pragma unroll
  for (int nt = 0; nt < 6; ++nt) qb[nt] = qkv_b[nb + nt * 16 + l15];

  // ---- qkv GEMM: M=64 (4 tiles), N=96/wave (6 tiles), K=128 (4 tiles) ----
  #pragma unroll
  for (int mt = 0; mt < 4; ++mt) {
    const int t = mt * 16 + l15;            // token for A-fragment row
    bf16x8 a[4];
    if (t < NTOK) {
      const float* src = xbase + ((t / 7) * 56 + (t % 7)) * CDIM + lg * 8;
      #pragma unroll
      for (int kt = 0; kt < 4; ++kt) {
        f32x4 x0 = *(const f32x4*)(src + kt * 32);
        f32x4 x1 = *(const f32x4*)(src + kt * 32 + 4);
        bf16x8 av;
        av[0] = (__bf16)x0[0]; av[1] = (__bf16)x0[1]; av[2] = (__bf16)x0[2]; av[3] = (__bf16)x0[3];
        av[4] = (__bf16)x1[0]; av[5] = (__bf16)x1[1]; av[6] = (__bf16)x1[2]; av[7] = (__bf16)x1[3];
        a[kt] = av;
      }
    } else {
      #pragma unroll
      for (int kt = 0; kt < 4; ++kt) {
        #pragma unroll
        for (int q2 = 0; q2 < 8; ++q2) a[kt][q2] = (__bf16)0.0f;
      }
    }
    f32x4 acc[6];
    #pragma unroll
    for (int nt = 0; nt < 6; ++nt) { acc[nt][0] = 0.f; acc[nt][1] = 0.f; acc[nt][2] = 0.f; acc[nt][3] = 0.f; }
    #pragma unroll
    for (int nt = 0; nt < 6; ++nt)
      #pragma unroll
      for (int kt = 0; kt < 4; ++kt)
        acc[nt] = __builtin_amdgcn_mfma_f32_16x16x32_bf16(a[kt], bq[nt][kt], acc[nt], 0, 0, 0);

    // epilogue: C-layout col = channel (nb+nt*16+l15), rows r0..r0+3
    const int r0 = mt * 16 + lg * 4;
    #pragma unroll
    for (int nt = 0; nt < 6; ++nt) {
      const int n = nb + nt * 16 + l15;     // 0..383; branch is wave-uniform per nt
      if (n < CDIM) {
        #pragma unroll
        for (int i = 0; i < 4; ++i)
          qs_[(r0 + i) * 136 + n] = (__bf16)(acc[nt][i] + qb[nt]);
      } else if (n < 2 * CDIM) {
        #pragma unroll
        for (int i = 0; i < 4; ++i)
          ks_[(r0 + i) * 136 + (n - CDIM)] = (__bf16)(acc[nt][i] + qb[nt]);
      } else {
        bf16x4 vv;                          // v stored transposed: vT[ch][token]
        #pragma unroll
        for (int i = 0; i < 4; ++i) vv[i] = (__bf16)(acc[nt][i] + qb[nt]);
        *(bf16x4*)(vT_ + (n - 2 * CDIM) * 72 + r0) = vv;
      }
    }
  }
  __syncthreads();

  __bf16* O_ = qs_;  // O aliases qs: head h reads Q cols h*32.. before writing O there; wave-local rows

  // ---- per-head attention: S = QK^T*scale + bias, softmax, O = P V ----
  for (int h = 0; h < NHEAD; ++h) {
    const int hc = h * HDIM;
    bf16x8 aqf = *(const bf16x8*)(qs_ + (m0 + l15) * 136 + hc + lg * 8);
    f32x4 s[4];
    #pragma unroll
    for (int nt = 0; nt < 4; ++nt) {
      bf16x8 bk = *(const bf16x8*)(ks_ + (nt * 16 + l15) * 136 + hc + lg * 8);
      f32x4 z; z[0] = 0.f; z[1] = 0.f; z[2] = 0.f; z[3] = 0.f;
      s[nt] = __builtin_amdgcn_mfma_f32_16x16x32_bf16(aqf, bk, z, 0, 0, 0);
    }
    // softmax over 64 cols; row r lives in 16 lanes (same lg), reg i
    const float* blh = blut + h * 4096;
    #pragma unroll
    for (int i = 0; i < 4; ++i) {
      const int r = m0 + lg * 4 + i;
      float v0 = s[0][i] * SCALE + blh[r * 64 + 0 + l15];
      float v1 = s[1][i] * SCALE + blh[r * 64 + 16 + l15];
      float v2 = s[2][i] * SCALE + blh[r * 64 + 32 + l15];
      float v3 = s[3][i] * SCALE + blh[r * 64 + 48 + l15];
      float mx = fmaxf(fmaxf(v0, v1), fmaxf(v2, v3));
      #pragma unroll
      for (int off = 1; off < 16; off <<= 1) mx = fmaxf(mx, __shfl_xor(mx, off));
      v0 = __expf(v0 - mx); v1 = __expf(v1 - mx);
      v2 = __expf(v2 - mx); v3 = __expf(v3 - mx);
      float sum = v0 + v1 + v2 + v3;
      #pragma unroll
      for (int off = 1; off < 16; off <<= 1) sum += __shfl_xor(sum, off);
      const float inv = 1.0f / sum;
      Pm_[r * 72 + 0 + l15]  = (__bf16)(v0 * inv);
      Pm_[r * 72 + 16 + l15] = (__bf16)(v1 * inv);
      Pm_[r * 72 + 32 + l15] = (__bf16)(v2 * inv);
      Pm_[r * 72 + 48 + l15] = (__bf16)(v3 * inv);
    }
    // PV: A = P (wave-local rows), B = vT (token-contiguous)
    f32x4 o0, o1;
    o0[0]=0.f;o0[1]=0.f;o0[2]=0.f;o0[3]=0.f; o1[0]=0.f;o1[1]=0.f;o1[2]=0.f;o1[3]=0.f;
    #pragma unroll
    for (int kt = 0; kt < 2; ++kt) {
      bf16x8 ap  = *(const bf16x8*)(Pm_ + (m0 + l15) * 72 + kt * 32 + lg * 8);
      bf16x8 bv0 = *(const bf16x8*)(vT_ + (hc + l15) * 72 + kt * 32 + lg * 8);
      bf16x8 bv1 = *(const bf16x8*)(vT_ + (hc + 16 + l15) * 72 + kt * 32 + lg * 8);
      o0 = __builtin_amdgcn_mfma_f32_16x16x32_bf16(ap, bv0, o0, 0, 0, 0);
      o1 = __builtin_amdgcn_mfma_f32_16x16x32_bf16(ap, bv1, o1, 0, 0, 0);
    }
    const int r0 = m0 + lg * 4;
    #pragma unroll
    for (int i = 0; i < 4; ++i) {
      O_[(r0 + i) * 136 + hc + l15]      = (__bf16)o0[i];
      O_[(r0 + i) * 136 + hc + 16 + l15] = (__bf16)o1[i];
    }
  }
  __syncthreads();   // proj reads O rows across waves

  // ---- proj GEMM: wave-chunked over N (32 cols), loop M-tiles ----
  const int nb2 = wave * 32;
  bf16x8 bp[2][4];
  #pragma unroll
  for (int nt = 0; nt < 2; ++nt)
    #pragma unroll
    for (int kt = 0; kt < 4; ++kt)
      bp[nt][kt] = *(const bf16x8*)(projT + (nb2 + nt * 16 + l15) * CDIM + kt * 32 + lg * 8);
  const float pb0 = proj_b[nb2 + l15];
  const float pb1 = proj_b[nb2 + 16 + l15];
  float* outw = out + (((b * 56) + wh * 7) * 56 + ww * 7) * CDIM;

  #pragma unroll
  for (int mt = 0; mt < 4; ++mt) {
    bf16x8 ao[4];
    #pragma unroll
    for (int kt = 0; kt < 4; ++kt)
      ao[kt] = *(const bf16x8*)(O_ + (mt * 16 + l15) * 136 + kt * 32 + lg * 8);
    f32x4 c0, c1;
    c0[0]=0.f;c0[1]=0.f;c0[2]=0.f;c0[3]=0.f; c1[0]=0.f;c1[1]=0.f;c1[2]=0.f;c1[3]=0.f;
    #pragma unroll
    for (int kt = 0; kt < 4; ++kt) {
      c0 = __builtin_amdgcn_mfma_f32_16x16x32_bf16(ao[kt], bp[0][kt], c0, 0, 0, 0);
      c1 = __builtin_amdgcn_mfma_f32_16x16x32_bf16(ao[kt], bp[1][kt], c1, 0, 0, 0);
    }
    #pragma unroll
    for (int i = 0; i < 4; ++i) {
      const int r = mt * 16 + lg * 4 + i;
      if (r < NTOK) {
        float* po = outw + ((r / 7) * 56 + (r % 7)) * CDIM + nb2;
        po[l15]      = c0[i] + pb0;
        po[16 + l15] = c1[i] + pb1;
      }
    }
  }
}

extern "C" void kernel_launch(void* const* d_in, const int* in_sizes, int n_in,
                              void* d_out, int out_size, void* d_ws, size_t ws_size,
                              hipStream_t stream) {
  const float* x          = (const float*)d_in[0];
  const float* qkv_w      = (const float*)d_in[1];
  const float* qkv_b      = (const float*)d_in[2];
  const float* proj_w     = (const float*)d_in[3];
  const float* proj_b     = (const float*)d_in[4];
  const float* bias_table = (const float*)d_in[5];

  __bf16* qkvT  = (__bf16*)d_ws;
  __bf16* projT = qkvT + C3 * CDIM;
  float*  blut  = (float*)((char*)d_ws + 131072);
  float*  out   = (float*)d_out;

  hipLaunchKernelGGL(prep_kernel, dim3(320), dim3(256), 0, stream,
                     qkv_w, proj_w, bias_table, qkvT, projT, blut);
  hipLaunchKernelGGL(attn_kernel, dim3(4096), dim3(256), 0, stream,
                     x, qkv_b, proj_b, qkvT, projT, blut, out);
}